// Round 2
// baseline (465.827 us; speedup 1.0000x reference)
//
#include <hip/hip_runtime.h>
#include <hip/hip_bf16.h>
#include <cstdint>

#define B_ 8
#define SYN_ 512
#define T_ 500
#define NT_ 549        // output timesteps = T + 2*48 - 48 + 1
#define OC_ 10
#define NEUR_ 64
#define ON_ 640
#define LCAP_ 32768    // max spike entries per batch (expected ~5120)
#define THETA_ 25.6f

// ---------------- workspace layout (bytes) ----------------
// pot   [B][NT][OC][NEUR] f32 : 0            .. 11,243,520
// offs  [B][501] int          : 11,243,520   .. 11,259,552
// lists [B][LCAP] u32         : 11,259,904   .. 12,308,480
// gmax  [B][NT] u32(f32 bits) : 12,308,480   .. 12,326,048
#define POT_OFF   0
#define OFFS_OFF  11243520
#define LIST_OFF  11259904
#define GMAX_OFF  12308480

__global__ void zerof4(float4* p, int n4) {
    int i = blockIdx.x * blockDim.x + threadIdx.x;
    int stride = gridDim.x * blockDim.x;
    float4 z = make_float4(0.f, 0.f, 0.f, 0.f);
    for (; i < n4; i += stride) p[i] = z;
}

// one block per batch, 512 threads: count spikes per t, exclusive scan,
// fill per-t s-sorted lists. Also zero gmax.
__global__ void build_lists(const float* __restrict__ x, int* __restrict__ offs,
                            unsigned int* __restrict__ lists, unsigned int* __restrict__ gmax) {
    int b = blockIdx.x;
    int tid = threadIdx.x;
    __shared__ int incl[512];
    for (int i = tid; i < NT_; i += 512) gmax[b * NT_ + i] = 0u;

    const float* xb = x + (size_t)b * SYN_ * T_;
    int c = 0;
    if (tid < T_) {
        #pragma unroll 8
        for (int s = 0; s < SYN_; ++s) c += (xb[s * T_ + tid] != 0.0f);
    }
    incl[tid] = c;
    __syncthreads();
    // Hillis-Steele inclusive scan over 512 slots
    for (int off = 1; off < 512; off <<= 1) {
        int v = incl[tid];
        int add = (tid >= off) ? incl[tid - off] : 0;
        __syncthreads();
        incl[tid] = v + add;
        __syncthreads();
    }
    if (tid < T_) offs[b * 501 + tid] = (tid == 0) ? 0 : incl[tid - 1];
    if (tid == 0) offs[b * 501 + T_] = incl[T_ - 1];
    // fill (thread owns one t -> deterministic s-ascending order)
    if (tid < T_ && c > 0) {
        int cur = (tid == 0) ? 0 : incl[tid - 1];
        unsigned int* lb = lists + (size_t)b * LCAP_;
        for (int s = 0; s < SYN_; ++s) {
            if (xb[s * T_ + tid] != 0.0f) {
                if (cur < LCAP_) lb[cur] = ((unsigned int)tid << 16) | (unsigned int)s;
                ++cur;
            }
        }
    }
}

// sparse conv: grid = 10 (o-chunk) x 8 (b) x 3 (tp-split) = 240 blocks, 512 thr
// LDS: w_lds[512][65] (tanh(weight), +1 pad) + offs_lds[512]
#define APPLY(W) { float w15 = (W) * 1.5f; \
    a0 += __builtin_amdgcn_fmed3f(0.0f, ts0, fmaf(ts0, -0.5f, w15)); \
    a1 += __builtin_amdgcn_fmed3f(0.0f, ts1, fmaf(ts1, -0.5f, w15)); \
    a2 += __builtin_amdgcn_fmed3f(0.0f, ts2, fmaf(ts2, -0.5f, w15)); \
    a3 += __builtin_amdgcn_fmed3f(0.0f, ts3, fmaf(ts3, -0.5f, w15)); }

__global__ __launch_bounds__(512) void conv_sparse(
        const float* __restrict__ weight, const float* __restrict__ bias,
        const int* __restrict__ offs, const unsigned int* __restrict__ lists,
        float* __restrict__ pot, unsigned int* __restrict__ gmax) {
    extern __shared__ float smem[];
    float* w_lds = smem;                       // [512][65]
    int* offs_lds = (int*)(smem + 512 * 65);   // [501]

    int bid = blockIdx.x;
    int o = bid % OC_;
    int b = (bid / OC_) % B_;
    int split = bid / (OC_ * B_);
    int p0 = split * 183, p1 = p0 + 183;

    int tid = threadIdx.x, lane = tid & 63, wv = tid >> 6;

    // stage tanh(weight) transposed: w_lds[s][n]
    for (int n = wv; n < 64; n += 8) {
        const float* wr = weight + (size_t)(o * 64 + n) * SYN_;
        for (int s0 = 0; s0 < SYN_; s0 += 64) {
            w_lds[(s0 + lane) * 65 + n] = tanhf(wr[s0 + lane]);
        }
    }
    for (int i = tid; i < 501; i += 512) offs_lds[i] = offs[b * 501 + i];
    __syncthreads();

    float bv = THETA_ * bias[o * 64 + lane];
    const unsigned int* lst = lists + (size_t)b * LCAP_;

    const int ntiles = 46;   // ceil(183/4)
    for (int tile = wv; tile < ntiles; tile += 8) {
        int tq = p0 + tile * 4;
        float a0 = bv, a1 = bv, a2 = bv, a3 = bv;
        int tlo = tq - 48; if (tlo < 0) tlo = 0;
        int thi = tq + 4;  if (thi > T_) thi = T_;
        float ts0 = (float)(tq - 1 - tlo) * 0.0625f;
        int segs = offs_lds[tlo];
        for (int t = tlo; t < thi; ++t) {
            int sege = offs_lds[t + 1];
            float ts1 = ts0 + 0.0625f, ts2 = ts0 + 0.125f, ts3 = ts0 + 0.1875f;
            int i = segs;
            for (; i + 3 < sege; i += 4) {   // group-of-4 to overlap latencies
                unsigned int e0 = lst[i], e1 = lst[i + 1], e2 = lst[i + 2], e3 = lst[i + 3];
                float w0 = w_lds[(e0 & 0xFFFF) * 65 + lane];
                float w1 = w_lds[(e1 & 0xFFFF) * 65 + lane];
                float w2 = w_lds[(e2 & 0xFFFF) * 65 + lane];
                float w3 = w_lds[(e3 & 0xFFFF) * 65 + lane];
                APPLY(w0); APPLY(w1); APPLY(w2); APPLY(w3);
            }
            for (; i < sege; ++i) {
                unsigned int e = lst[i];
                float w = w_lds[(e & 0xFFFF) * 65 + lane];
                APPLY(w);
            }
            segs = sege;
            ts0 -= 0.0625f;
        }
        // store + per-(b,t) unmasked max for WTA fast path
        #pragma unroll
        for (int j = 0; j < 4; ++j) {
            int tqj = tq + j;
            if (tqj < p1) {
                float a = (j == 0) ? a0 : (j == 1) ? a1 : (j == 2) ? a2 : a3;
                pot[((size_t)(b * NT_ + tqj) * OC_ + o) * 64 + lane] = a;
                float m = a;
                #pragma unroll
                for (int k = 32; k >= 1; k >>= 1) m = fmaxf(m, __shfl_xor(m, k));
                if (lane == 0) atomicMax(&gmax[b * NT_ + tqj], __float_as_uint(m));
            }
        }
    }
}

// sequential k-WTA: one wave (64 lanes = 64 neurons) per batch
__global__ void wta(const float* __restrict__ pot, const unsigned int* __restrict__ gmax,
                    float* __restrict__ out) {
    int b = blockIdx.x;
    int lane = threadIdx.x;
    int dep = 0;
    for (int t0 = 0; t0 < NT_; t0 += 64) {
        int cl = NT_ - t0; if (cl > 64) cl = 64;
        float gv = 0.f;
        if (lane < cl) gv = __uint_as_float(gmax[b * NT_ + t0 + lane]);
        unsigned long long mask = __ballot(gv > THETA_);
        int prev = -1;
        while (mask) {
            int p = __builtin_ctzll(mask); mask &= mask - 1;
            dep -= (p - prev - 1); if (dep < 0) dep = 0;   // fast-forward decay
            prev = p;
            int tt = t0 + p;
            // full step
            unsigned long long db = __ballot(dep != 0);
            bool k_ok = __popcll(db) < 16;
            float m = 0.f; int io = 0;
            if (k_ok && dep == 0) {
                const float* row = pot + ((size_t)(b * NT_ + tt) * OC_) * 64 + lane;
                #pragma unroll
                for (int oo = 0; oo < OC_; ++oo) {
                    float v = row[oo * 64];
                    if (v > m) { m = v; io = oo; }
                }
            }
            int flat = lane * OC_ + io;   // n*10+o, reference flatten order
            #pragma unroll
            for (int k = 1; k < 64; k <<= 1) {
                float vm = __shfl_xor(m, k);
                int vf = __shfl_xor(flat, k);
                if (vm > m || (vm == m && vf < flat)) { m = vm; flat = vf; }
            }
            if (m > THETA_) {
                int wn = flat / OC_, wo = flat - wn * OC_;
                if (lane == wn) {
                    dep = 48;   // becomes 47 after the -1 below
                    out[((size_t)((b * OC_ + wo) * NEUR_ + wn)) * NT_ + tt] = 1.0f;
                }
            }
            dep -= 1; if (dep < 0) dep = 0;
        }
        dep -= (cl - 1 - prev); if (dep < 0) dep = 0;
    }
}

extern "C" void kernel_launch(void* const* d_in, const int* in_sizes, int n_in,
                              void* d_out, int out_size, void* d_ws, size_t ws_size,
                              hipStream_t stream) {
    const float* x      = (const float*)d_in[0];   // [8,1,512,500]
    const float* weight = (const float*)d_in[1];   // [640,512]
    const float* bias   = (const float*)d_in[2];   // [640]
    float* out = (float*)d_out;

    char* ws = (char*)d_ws;
    float*        pot   = (float*)(ws + POT_OFF);
    int*          offs  = (int*)(ws + OFFS_OFF);
    unsigned int* lists = (unsigned int*)(ws + LIST_OFF);
    unsigned int* gmaxp = (unsigned int*)(ws + GMAX_OFF);

    // zero output (poisoned 0xAA before every call)
    hipLaunchKernelGGL(zerof4, dim3(1024), dim3(256), 0, stream,
                       (float4*)out, out_size / 4);

    hipLaunchKernelGGL(build_lists, dim3(B_), dim3(512), 0, stream,
                       x, offs, lists, gmaxp);

    size_t shmem = (512 * 65 + 512) * sizeof(float);   // 135,168 B
    hipFuncSetAttribute((const void*)conv_sparse,
                        hipFuncAttributeMaxDynamicSharedMemorySize, (int)shmem);
    hipLaunchKernelGGL(conv_sparse, dim3(240), dim3(512), shmem, stream,
                       weight, bias, offs, lists, pot, gmaxp);

    hipLaunchKernelGGL(wta, dim3(B_), dim3(64), 0, stream, pot, gmaxp, out);
}

// Round 4
// 435.133 us; speedup vs baseline: 1.0705x; 1.0705x over previous
//
#include <hip/hip_runtime.h>
#include <hip/hip_bf16.h>
#include <cstdint>

#define B_ 8
#define SYN_ 512
#define T_ 500
#define NT_ 549        // output timesteps
#define OC_ 10
#define NEUR_ 64
#define LCAP_ 8192     // max spike entries per batch (expected ~5120)
#define THETA_ 25.6f

// ---------------- workspace layout (bytes) ----------------
#define OFFS_OFF  0          // [B][501] int            (16,032)
#define LIST_OFF  16384      // [B][LCAP] u32           (262,144)
#define WT_OFF    278528     // [OC][SYN][64] f32 = 1.5*tanh(w), n-contig (1,310,720)
#define WALL_OFF  1589248    // [OC] u32 (f32 bits) max of wt per o (40)
#define MAXN_OFF  1589760    // [B][NT][64] u64 key = (potbits<<32)|(9-o) (2,248,704)
#define GMAX_OFF  3838464    // [B][NT] u32 (f32 bits) unmasked max (17,568)

__global__ void zerof4(float4* p, int n4) {
    int i = blockIdx.x * blockDim.x + threadIdx.x;
    int stride = gridDim.x * blockDim.x;
    float4 z = make_float4(0.f, 0.f, 0.f, 0.f);
    for (; i < n4; i += stride) p[i] = z;
}

// one block per batch, 512 threads: per-t spike counts, scan, s-sorted lists.
// Also zeroes gmax, maxn, wall (wall zeroed by block 0 before prep runs).
__global__ void build_lists(const float* __restrict__ x, int* __restrict__ offs,
                            unsigned int* __restrict__ lists,
                            unsigned long long* __restrict__ maxn,
                            unsigned int* __restrict__ gmax,
                            unsigned int* __restrict__ wall) {
    int b = blockIdx.x;
    int tid = threadIdx.x;
    __shared__ int incl[512];
    for (int i = tid; i < NT_; i += 512) gmax[b * NT_ + i] = 0u;
    unsigned long long* mz = maxn + (size_t)b * NT_ * 64;
    for (int i = tid; i < NT_ * 64; i += 512) mz[i] = 0ull;
    if (b == 0 && tid < OC_) wall[tid] = 0u;

    const float* xb = x + (size_t)b * SYN_ * T_;
    int c = 0;
    if (tid < T_) {
        #pragma unroll 8
        for (int s = 0; s < SYN_; ++s) c += (xb[s * T_ + tid] != 0.0f);
    }
    incl[tid] = c;
    __syncthreads();
    for (int off = 1; off < 512; off <<= 1) {
        int v = incl[tid];
        int add = (tid >= off) ? incl[tid - off] : 0;
        __syncthreads();
        incl[tid] = v + add;
        __syncthreads();
    }
    if (tid < T_) offs[b * 501 + tid] = (tid == 0) ? 0 : incl[tid - 1];
    if (tid == 0) offs[b * 501 + T_] = incl[T_ - 1];
    if (tid < T_ && c > 0) {
        int cur = (tid == 0) ? 0 : incl[tid - 1];
        unsigned int* lb = lists + (size_t)b * LCAP_;
        for (int s = 0; s < SYN_; ++s) {
            if (xb[s * T_ + tid] != 0.0f) {
                if (cur < LCAP_) lb[cur] = ((unsigned int)tid << 16) | (unsigned int)s;
                ++cur;
            }
        }
    }
}

// wt[o][s][n] = 1.5*tanh(weight[o*64+n][s]); wall[o] = max over (s,n).
// one wave per (o,n): lanes cover s (coalesced reads; scattered 4B writes, one-time).
__global__ __launch_bounds__(256) void prep(const float* __restrict__ weight,
                                            float* __restrict__ wt,
                                            unsigned int* __restrict__ wall) {
    int wid = (blockIdx.x * 256 + threadIdx.x) >> 6;   // 0..639
    int lane = threadIdx.x & 63;
    int o = wid >> 6, n = wid & 63;
    const float* wr = weight + (size_t)(o * 64 + n) * SYN_;
    float mx = 0.f;
    for (int s0 = 0; s0 < SYN_; s0 += 64) {
        int s = s0 + lane;
        float w15 = 1.5f * tanhf(wr[s]);
        wt[((size_t)(o * SYN_ + s) << 6) + n] = w15;
        mx = fmaxf(mx, w15);
    }
    #pragma unroll
    for (int k = 32; k >= 1; k >>= 1) mx = fmaxf(mx, __shfl_xor(mx, k));
    if (lane == 0) atomicMax(&wall[o], __float_as_uint(mx));
}

// sparse conv, LDS-free: grid = 16 (t-split) x 8 (b) x 10 (o) = 1280 blocks, 256 thr.
// Contribution of spike (s,t) to output tq+j: med3(0, ts, w15 - ts/2), ts=(tq+j-1-t)/16.
// Exactly zero when d >= 32*w15 -> window shrink via per-o max (RALL) skips only
// exact zeros: pot bits identical to the full-window version.
__global__ __launch_bounds__(256) void conv2(
        const float* __restrict__ wt, const float* __restrict__ bias,
        const unsigned int* __restrict__ wall,
        const int* __restrict__ offs, const unsigned int* __restrict__ lists,
        unsigned long long* __restrict__ maxn, unsigned int* __restrict__ gmax) {
    int bid = blockIdx.x;
    int sp = bid & 15;
    int b  = (bid >> 4) & 7;
    int o  = bid >> 7;
    int lane = threadIdx.x & 63, wv = threadIdx.x >> 6;

    float bv = THETA_ * bias[o * 64 + lane];
    float RALL = 32.0f * __uint_as_float(wall[o]);
    const float* wto = wt + ((size_t)o * SYN_ << 6);
    const unsigned int* lst = lists + (size_t)b * LCAP_;
    const int* ob = offs + b * 501;
    unsigned long long* mb = maxn + (size_t)b * NT_ * 64;
    unsigned int* gb = gmax + b * NT_;

    int tend = sp * 9 + 9; if (tend > 138) tend = 138;   // 138 tiles of 4 t' each
    for (int tile = sp * 9 + wv; tile < tend; tile += 4) {
        int tq = tile << 2;
        float a0 = bv, a1 = bv, a2 = bv, a3 = bv;
        int thi = tq + 3; if (thi > T_) thi = T_;
        int tlo = (int)floorf((float)(tq - 1) - RALL) + 1;
        if (tlo < 0) tlo = 0;
        if (tlo > thi) tlo = thi;
        int i1 = ob[thi];
        for (int i = ob[tlo]; i < i1; ++i) {
            unsigned int e = lst[i];
            int s = e & 0xFFFF;
            int t = e >> 16;
            float w15 = wto[(s << 6) + lane];
            float ts0 = (float)(tq - 1 - t) * 0.0625f;
            float ts1 = ts0 + 0.0625f, ts2 = ts0 + 0.125f, ts3 = ts0 + 0.1875f;
            a0 += __builtin_amdgcn_fmed3f(0.0f, ts0, fmaf(ts0, -0.5f, w15));
            a1 += __builtin_amdgcn_fmed3f(0.0f, ts1, fmaf(ts1, -0.5f, w15));
            a2 += __builtin_amdgcn_fmed3f(0.0f, ts2, fmaf(ts2, -0.5f, w15));
            a3 += __builtin_amdgcn_fmed3f(0.0f, ts3, fmaf(ts3, -0.5f, w15));
        }
        #pragma unroll
        for (int j = 0; j < 4; ++j) {
            int tt = tq + j;
            if (tt >= NT_) break;
            float a = (j == 0) ? a0 : (j == 1) ? a1 : (j == 2) ? a2 : a3;
            unsigned long long key =
                ((unsigned long long)__float_as_uint(a) << 32) | (unsigned int)(9 - o);
            atomicMax(&mb[(size_t)tt * 64 + lane], key);
            float m = a;
            #pragma unroll
            for (int k = 32; k >= 1; k >>= 1) m = fmaxf(m, __shfl_xor(m, k));
            if (lane == 0) atomicMax(&gb[tt], __float_as_uint(m));
        }
    }
}

// sequential k-WTA: one wave per batch. Candidate steps from gmax (>theta);
// masked argmax per candidate from maxn keys (one coalesced 512B load),
// depth-2 software pipeline on the key loads.
__global__ void wta2(const unsigned long long* __restrict__ maxn,
                     const unsigned int* __restrict__ gmax,
                     float* __restrict__ out) {
    int b = blockIdx.x;
    int lane = threadIdx.x;
    const unsigned long long* mb = maxn + (size_t)b * NT_ * 64;
    int dep = 0;
    for (int t0 = 0; t0 < NT_; t0 += 64) {
        int cl = NT_ - t0; if (cl > 64) cl = 64;
        float gv = (lane < cl) ? __uint_as_float(gmax[b * NT_ + t0 + lane]) : 0.f;
        unsigned long long mask = __ballot(gv > THETA_);
        int prev = -1;
        int p = 0;
        unsigned long long keyn = 0ull;
        if (mask) {
            p = __builtin_ctzll(mask);
            keyn = mb[(size_t)(t0 + p) * 64 + lane];
        }
        while (mask) {
            int pc = p;
            unsigned long long key = keyn;
            mask &= mask - 1;
            if (mask) {                       // prefetch next candidate
                p = __builtin_ctzll(mask);
                keyn = mb[(size_t)(t0 + p) * 64 + lane];
            }
            dep -= (pc - prev - 1); if (dep < 0) dep = 0;   // gap decay
            prev = pc;
            unsigned long long db = __ballot(dep != 0);
            bool k_ok = __popcll(db) < 16;
            unsigned long long kv = (k_ok && dep == 0) ? key : 0ull;
            int idx = lane;
            #pragma unroll
            for (int k = 1; k < 64; k <<= 1) {
                unsigned long long ok2 = __shfl_xor(kv, k);
                int oi = __shfl_xor(idx, k);
                unsigned int vc = (unsigned int)(kv >> 32);
                unsigned int vo = (unsigned int)(ok2 >> 32);
                if (vo > vc || (vo == vc && oi < idx)) { kv = ok2; idx = oi; }
            }
            float val = __uint_as_float((unsigned int)(kv >> 32));
            if (val > THETA_) {
                int wo = 9 - (int)(kv & 0xFFFFFFFFull);
                if (lane == idx) {
                    out[((size_t)((b * OC_ + wo) * NEUR_ + idx)) * NT_ + (t0 + pc)] = 1.0f;
                    dep = 48;   // 47 after the -1 below
                }
            }
            dep -= 1; if (dep < 0) dep = 0;
        }
        dep -= (cl - 1 - prev); if (dep < 0) dep = 0;
    }
}

extern "C" void kernel_launch(void* const* d_in, const int* in_sizes, int n_in,
                              void* d_out, int out_size, void* d_ws, size_t ws_size,
                              hipStream_t stream) {
    const float* x      = (const float*)d_in[0];   // [8,1,512,500]
    const float* weight = (const float*)d_in[1];   // [640,512]
    const float* bias   = (const float*)d_in[2];   // [640]
    float* out = (float*)d_out;

    char* ws = (char*)d_ws;
    int*                offs  = (int*)(ws + OFFS_OFF);
    unsigned int*       lists = (unsigned int*)(ws + LIST_OFF);
    float*              wt    = (float*)(ws + WT_OFF);
    unsigned int*       wall  = (unsigned int*)(ws + WALL_OFF);
    unsigned long long* maxn  = (unsigned long long*)(ws + MAXN_OFF);
    unsigned int*       gmaxp = (unsigned int*)(ws + GMAX_OFF);

    hipLaunchKernelGGL(zerof4, dim3(1024), dim3(256), 0, stream,
                       (float4*)out, out_size / 4);
    hipLaunchKernelGGL(build_lists, dim3(B_), dim3(512), 0, stream,
                       x, offs, lists, maxn, gmaxp, wall);
    hipLaunchKernelGGL(prep, dim3(160), dim3(256), 0, stream, weight, wt, wall);
    hipLaunchKernelGGL(conv2, dim3(1280), dim3(256), 0, stream,
                       wt, bias, wall, offs, lists, maxn, gmaxp);
    hipLaunchKernelGGL(wta2, dim3(B_), dim3(64), 0, stream, maxn, gmaxp, out);
}

// Round 13
// 284.878 us; speedup vs baseline: 1.6352x; 1.5274x over previous
//
#include <hip/hip_runtime.h>
#include <hip/hip_bf16.h>
#include <cstdint>

#define B_ 8
#define SYN_ 512
#define T_ 500
#define NT_ 549        // output timesteps
#define OC_ 10
#define NEUR_ 64
#define LCAP_ 8192     // max spike entries per batch (expected ~5120)
#define THETA_ 25.6f

// ---------------- workspace layout (bytes) ----------------
#define OFFS_OFF  0          // [B][501] int            (16,032)
#define LIST_OFF  16384      // [B][LCAP] u32           (262,144)
#define WT_OFF    278528     // [OC][SYN][64] f32 = 1.5*tanh(w), n-contig (1,310,720)
#define WALL_OFF  1589248    // [OC] u32 (f32 bits) max of wt per o (40)
#define MAXN_OFF  1589760    // [B][NT][64] u64 key = (potbits<<32)|(9-o) (2,248,704)
#define GMAX_OFF  3838464    // [B][NT] u32 (f32 bits) unmasked max (17,568)

__global__ void zerof4(float4* p, int n4) {
    int i = blockIdx.x * blockDim.x + threadIdx.x;
    int stride = gridDim.x * blockDim.x;
    float4 z = make_float4(0.f, 0.f, 0.f, 0.f);
    for (; i < n4; i += stride) p[i] = z;
}

// one block per batch, 512 threads: per-t spike counts, scan, s-sorted lists.
// Also zeroes gmax, maxn, wall.
__global__ void build_lists(const float* __restrict__ x, int* __restrict__ offs,
                            unsigned int* __restrict__ lists,
                            unsigned long long* __restrict__ maxn,
                            unsigned int* __restrict__ gmax,
                            unsigned int* __restrict__ wall) {
    int b = blockIdx.x;
    int tid = threadIdx.x;
    __shared__ int incl[512];
    for (int i = tid; i < NT_; i += 512) gmax[b * NT_ + i] = 0u;
    unsigned long long* mz = maxn + (size_t)b * NT_ * 64;
    for (int i = tid; i < NT_ * 64; i += 512) mz[i] = 0ull;
    if (b == 0 && tid < OC_) wall[tid] = 0u;

    const float* xb = x + (size_t)b * SYN_ * T_;
    int c = 0;
    if (tid < T_) {
        #pragma unroll 8
        for (int s = 0; s < SYN_; ++s) c += (xb[s * T_ + tid] != 0.0f);
    }
    incl[tid] = c;
    __syncthreads();
    for (int off = 1; off < 512; off <<= 1) {
        int v = incl[tid];
        int add = (tid >= off) ? incl[tid - off] : 0;
        __syncthreads();
        incl[tid] = v + add;
        __syncthreads();
    }
    if (tid < T_) offs[b * 501 + tid] = (tid == 0) ? 0 : incl[tid - 1];
    if (tid == 0) offs[b * 501 + T_] = incl[T_ - 1];
    if (tid < T_ && c > 0) {
        int cur = (tid == 0) ? 0 : incl[tid - 1];
        unsigned int* lb = lists + (size_t)b * LCAP_;
        for (int s = 0; s < SYN_; ++s) {
            if (xb[s * T_ + tid] != 0.0f) {
                if (cur < LCAP_) lb[cur] = ((unsigned int)tid << 16) | (unsigned int)s;
                ++cur;
            }
        }
    }
}

// wt[o][s][n] = 1.5*tanh(weight[o*64+n][s]); wall[o] = max over (s,n).
__global__ __launch_bounds__(256) void prep(const float* __restrict__ weight,
                                            float* __restrict__ wt,
                                            unsigned int* __restrict__ wall) {
    int wid = (blockIdx.x * 256 + threadIdx.x) >> 6;   // 0..639
    int lane = threadIdx.x & 63;
    int o = wid >> 6, n = wid & 63;
    const float* wr = weight + (size_t)(o * 64 + n) * SYN_;
    float mx = 0.f;
    for (int s0 = 0; s0 < SYN_; s0 += 64) {
        int s = s0 + lane;
        float w15 = 1.5f * tanhf(wr[s]);
        wt[((size_t)(o * SYN_ + s) << 6) + n] = w15;
        mx = fmaxf(mx, w15);
    }
    #pragma unroll
    for (int k = 32; k >= 1; k >>= 1) mx = fmaxf(mx, __shfl_xor(mx, k));
    if (lane == 0) atomicMax(&wall[o], __float_as_uint(mx));
}

// sparse conv v3: 8-output tiles, 4-spike unrolled loads, theta-gated atomics.
// grid = 80 (b,o) x 18 (split), 256 thr; wave handles tile = split*4 + wv.
// Contribution med3(0, ts, w15 - ts/2) is exactly 0 when ts >= 2*w15 -> the
// RALL window skip drops only exact zeros (bit-identical accumulation).
#define SPIKE8(F, W) { \
    _Pragma("unroll") \
    for (int j = 0; j < 8; ++j) { \
        float ts = (F) + (float)j * 0.0625f; \
        a[j] += __builtin_amdgcn_fmed3f(0.0f, ts, fmaf(ts, -0.5f, (W))); \
    } }

__global__ __launch_bounds__(256) void conv3(
        const float* __restrict__ wt, const float* __restrict__ bias,
        const unsigned int* __restrict__ wall,
        const int* __restrict__ offs, const unsigned int* __restrict__ lists,
        unsigned long long* __restrict__ maxn, unsigned int* __restrict__ gmax) {
    int bid = blockIdx.x;
    int sp = bid % 18;
    int bo = bid / 18;
    int b = bo & 7;
    int o = bo >> 3;
    int lane = threadIdx.x & 63, wv = threadIdx.x >> 6;
    int tile = sp * 4 + wv;
    if (tile >= 69) return;            // ceil(549/8) tiles
    int tq = tile << 3;

    float bv = THETA_ * bias[o * 64 + lane];
    float RALL = 32.0f * __uint_as_float(wall[o]);
    const float* wto = wt + ((size_t)o * SYN_ << 6);
    const unsigned int* lst = lists + (size_t)b * LCAP_;
    const int* ob = offs + b * 501;
    unsigned long long* mb = maxn + (size_t)b * NT_ * 64;
    unsigned int* gb = gmax + b * NT_;

    float a[8];
    #pragma unroll
    for (int j = 0; j < 8; ++j) a[j] = bv;

    int thi = tq + 7; if (thi > T_) thi = T_;
    int tlo = (int)floorf((float)(tq - 1) - RALL) + 1;
    if (tlo < 0) tlo = 0;
    if (tlo > thi) tlo = thi;

    int i = ob[tlo], i1 = ob[thi];
    for (; i + 3 < i1; i += 4) {       // batch 4 list + 4 weight loads
        unsigned int e0 = lst[i], e1 = lst[i+1], e2 = lst[i+2], e3 = lst[i+3];
        float w0 = wto[((e0 & 0xFFFF) << 6) + lane];
        float w1 = wto[((e1 & 0xFFFF) << 6) + lane];
        float w2 = wto[((e2 & 0xFFFF) << 6) + lane];
        float w3 = wto[((e3 & 0xFFFF) << 6) + lane];
        float f0 = (float)(tq - 1 - (int)(e0 >> 16)) * 0.0625f;
        float f1 = (float)(tq - 1 - (int)(e1 >> 16)) * 0.0625f;
        float f2 = (float)(tq - 1 - (int)(e2 >> 16)) * 0.0625f;
        float f3 = (float)(tq - 1 - (int)(e3 >> 16)) * 0.0625f;
        SPIKE8(f0, w0); SPIKE8(f1, w1); SPIKE8(f2, w2); SPIKE8(f3, w3);
    }
    for (; i < i1; ++i) {
        unsigned int e = lst[i];
        float w = wto[((e & 0xFFFF) << 6) + lane];
        float f = (float)(tq - 1 - (int)(e >> 16)) * 0.0625f;
        SPIKE8(f, w);
    }

    #pragma unroll
    for (int j = 0; j < 8; ++j) {
        int tt = tq + j;
        if (tt >= NT_) break;
        float aj = a[j];
        // sub-theta values never change a WTA decision -> gate both atomics
        if (__any(aj > THETA_)) {
            if (aj > THETA_) {
                unsigned long long key =
                    ((unsigned long long)__float_as_uint(aj) << 32) | (unsigned int)(9 - o);
                atomicMax(&mb[(size_t)tt * 64 + lane], key);
            }
            float m = aj;
            #pragma unroll
            for (int k = 32; k >= 1; k >>= 1) m = fmaxf(m, __shfl_xor(m, k));
            if (lane == 0) atomicMax(&gb[tt], __float_as_uint(m));
        }
    }
}

// sequential k-WTA: one wave per batch; candidates from gmax, keys from maxn.
__global__ void wta2(const unsigned long long* __restrict__ maxn,
                     const unsigned int* __restrict__ gmax,
                     float* __restrict__ out) {
    int b = blockIdx.x;
    int lane = threadIdx.x;
    const unsigned long long* mb = maxn + (size_t)b * NT_ * 64;
    int dep = 0;
    for (int t0 = 0; t0 < NT_; t0 += 64) {
        int cl = NT_ - t0; if (cl > 64) cl = 64;
        float gv = (lane < cl) ? __uint_as_float(gmax[b * NT_ + t0 + lane]) : 0.f;
        unsigned long long mask = __ballot(gv > THETA_);
        int prev = -1;
        int p = 0;
        unsigned long long keyn = 0ull;
        if (mask) {
            p = __builtin_ctzll(mask);
            keyn = mb[(size_t)(t0 + p) * 64 + lane];
        }
        while (mask) {
            int pc = p;
            unsigned long long key = keyn;
            mask &= mask - 1;
            if (mask) {                       // prefetch next candidate
                p = __builtin_ctzll(mask);
                keyn = mb[(size_t)(t0 + p) * 64 + lane];
            }
            dep -= (pc - prev - 1); if (dep < 0) dep = 0;   // gap decay
            prev = pc;
            unsigned long long db = __ballot(dep != 0);
            bool k_ok = __popcll(db) < 16;
            unsigned long long kv = (k_ok && dep == 0) ? key : 0ull;
            int idx = lane;
            #pragma unroll
            for (int k = 1; k < 64; k <<= 1) {
                unsigned long long ok2 = __shfl_xor(kv, k);
                int oi = __shfl_xor(idx, k);
                unsigned int vc = (unsigned int)(kv >> 32);
                unsigned int vo = (unsigned int)(ok2 >> 32);
                if (vo > vc || (vo == vc && oi < idx)) { kv = ok2; idx = oi; }
            }
            float val = __uint_as_float((unsigned int)(kv >> 32));
            if (val > THETA_) {
                int wo = 9 - (int)(kv & 0xFFFFFFFFull);
                if (lane == idx) {
                    out[((size_t)((b * OC_ + wo) * NEUR_ + idx)) * NT_ + (t0 + pc)] = 1.0f;
                    dep = 48;   // 47 after the -1 below
                }
            }
            dep -= 1; if (dep < 0) dep = 0;
        }
        dep -= (cl - 1 - prev); if (dep < 0) dep = 0;
    }
}

extern "C" void kernel_launch(void* const* d_in, const int* in_sizes, int n_in,
                              void* d_out, int out_size, void* d_ws, size_t ws_size,
                              hipStream_t stream) {
    const float* x      = (const float*)d_in[0];   // [8,1,512,500]
    const float* weight = (const float*)d_in[1];   // [640,512]
    const float* bias   = (const float*)d_in[2];   // [640]
    float* out = (float*)d_out;

    char* ws = (char*)d_ws;
    int*                offs  = (int*)(ws + OFFS_OFF);
    unsigned int*       lists = (unsigned int*)(ws + LIST_OFF);
    float*              wt    = (float*)(ws + WT_OFF);
    unsigned int*       wall  = (unsigned int*)(ws + WALL_OFF);
    unsigned long long* maxn  = (unsigned long long*)(ws + MAXN_OFF);
    unsigned int*       gmaxp = (unsigned int*)(ws + GMAX_OFF);

    hipLaunchKernelGGL(zerof4, dim3(1024), dim3(256), 0, stream,
                       (float4*)out, out_size / 4);
    hipLaunchKernelGGL(build_lists, dim3(B_), dim3(512), 0, stream,
                       x, offs, lists, maxn, gmaxp, wall);
    hipLaunchKernelGGL(prep, dim3(160), dim3(256), 0, stream, weight, wt, wall);
    hipLaunchKernelGGL(conv3, dim3(1440), dim3(256), 0, stream,
                       wt, bias, wall, offs, lists, maxn, gmaxp);
    hipLaunchKernelGGL(wta2, dim3(B_), dim3(64), 0, stream, maxn, gmaxp, out);
}

// Round 14
// 284.833 us; speedup vs baseline: 1.6354x; 1.0002x over previous
//
#include <hip/hip_runtime.h>
#include <hip/hip_bf16.h>
#include <cstdint>

#define B_ 8
#define SYN_ 512
#define T_ 500
#define NT_ 549        // output timesteps
#define OC_ 10
#define NEUR_ 64
#define LCAP_ 8192
#define THETA_ 25.6f

// ---------------- workspace layout (bytes) ----------------
#define OFFS_OFF  0          // [B][501] int              (16,032)
#define LIST_OFF  16384      // [B][LCAP] u32             (262,144)
#define WT_OFF    278528     // [OC][SYN][64] f32 1.5*tanh (1,310,720)
#define WALL_OFF  1589248    // [OC] u32 max w15 per o    (40)
#define RMAX_OFF  1589504    // [OC][SYN] f32 2*max_n w15 (20,480)
#define MAXN_OFF  1610240    // [B][NT][64] u64 keys      (2,248,704)
#define GMAX_OFF  3859200    // [B][NT] u32               (17,568)
#define CNT_OFF   3877120    // [B][512] int              (16,384)
// zero range covering maxn..gmax end (16B aligned, includes harmless gap)
#define NMZ4 ((GMAX_OFF + 17568 - MAXN_OFF) / 16)   // 141,658 float4

// K1: 64 blocks x 64 thr. Zero out/maxn/gmax/wall (grid-stride) + per-(b,t)
// spike counts (coalesced: consecutive threads -> consecutive t).
__global__ __launch_bounds__(64) void count_zero(
        const float* __restrict__ x, int* __restrict__ cnt,
        float4* __restrict__ out4, int nout4, float4* __restrict__ mz4,
        unsigned int* __restrict__ wall) {
    int i = blockIdx.x * 64 + threadIdx.x;   // 0..4095
    int nt = gridDim.x * 64;
    float4 z = make_float4(0.f, 0.f, 0.f, 0.f);
    for (int k = i; k < nout4; k += nt) out4[k] = z;
    for (int k = i; k < NMZ4; k += nt) mz4[k] = z;
    if (i < OC_) wall[i] = 0u;
    int b = i >> 9, t = i & 511;
    if (t < T_) {
        const float* xb = x + (size_t)b * SYN_ * T_ + t;
        int c = 0;
        #pragma unroll 8
        for (int s = 0; s < SYN_; ++s) c += (xb[s * T_] != 0.0f);
        cnt[(b << 9) | t] = c;
    }
}

// K2: exclusive scan of per-t counts -> offs. 8 blocks x 512.
__global__ void scan_offs(const int* __restrict__ cnt, int* __restrict__ offs) {
    int b = blockIdx.x, tid = threadIdx.x;
    __shared__ int incl[512];
    incl[tid] = (tid < T_) ? cnt[(b << 9) | tid] : 0;
    __syncthreads();
    for (int off = 1; off < 512; off <<= 1) {
        int v = incl[tid];
        int add = (tid >= off) ? incl[tid - off] : 0;
        __syncthreads();
        incl[tid] = v + add;
        __syncthreads();
    }
    if (tid < T_) offs[b * 501 + tid] = tid ? incl[tid - 1] : 0;
    if (tid == 0) offs[b * 501 + T_] = incl[T_ - 1];
}

// K3: fill s-sorted per-t lists. 64 blocks x 64 thr, thread owns (b,t).
__global__ __launch_bounds__(64) void fill_lists(
        const float* __restrict__ x, const int* __restrict__ offs,
        unsigned int* __restrict__ lists) {
    int i = blockIdx.x * 64 + threadIdx.x;
    int b = i >> 9, t = i & 511;
    if (t >= T_) return;
    const float* xb = x + (size_t)b * SYN_ * T_ + t;
    int cur = offs[b * 501 + t];
    unsigned int* lb = lists + (size_t)b * LCAP_;
    for (int s = 0; s < SYN_; ++s) {
        if (xb[s * T_] != 0.0f) {
            if (cur < LCAP_) lb[cur] = ((unsigned int)t << 16) | (unsigned int)s;
            ++cur;
        }
    }
}

// K4: wt[o][s][n]=1.5*tanh(w), coalesced both sides via LDS 64x64 transpose;
// rmax2[o][s]=2*max_n w15 (running max in read phase); wall[o]=max w15.
// 40 blocks x 128 (2 waves, 1 tile each). LDS 2*64*65*4 = 33,280 B.
__global__ __launch_bounds__(128) void prep2(
        const float* __restrict__ weight, float* __restrict__ wt,
        float* __restrict__ rmax2, unsigned int* __restrict__ wall) {
    __shared__ float tile[2][64][65];
    int wv = threadIdx.x >> 6, lane = threadIdx.x & 63;
    int tid4 = blockIdx.x * 2 + wv;          // 0..79
    int o = tid4 >> 3, sc = (tid4 & 7) << 6;
    float (*td)[65] = tile[wv];
    float mx = 0.f;
    for (int n = 0; n < 64; ++n) {
        float w15 = 1.5f * tanhf(weight[(size_t)(o * 64 + n) * SYN_ + sc + lane]);
        td[n][lane] = w15;
        mx = fmaxf(mx, w15);   // running max over n for s'=lane
    }
    rmax2[o * SYN_ + sc + lane] = 2.0f * mx;
    float wm = mx;
    #pragma unroll
    for (int k = 32; k >= 1; k >>= 1) wm = fmaxf(wm, __shfl_xor(wm, k));
    if (lane == 0) atomicMax(&wall[o], __float_as_uint(wm));
    for (int r = 0; r < 64; ++r)             // wave-private tile: no barrier
        wt[((size_t)(o * SYN_ + sc + r) << 6) + lane] = td[lane][r];
}

// K5: sparse conv, 8-output tiles, 4-spike batches, per-(o,s) rmax gate.
// f >= rm  =>  d >= 32*w15[n] for all n  =>  med3 contribution exactly 0.0f
// (exact: both sides scale by powers of two). Skip is wave-uniform.
#define SPIKE8(F, W) { \
    _Pragma("unroll") \
    for (int j = 0; j < 8; ++j) { \
        float ts = (F) + (float)j * 0.0625f; \
        a[j] += __builtin_amdgcn_fmed3f(0.0f, ts, fmaf(ts, -0.5f, (W))); \
    } }

__global__ __launch_bounds__(256) void conv4(
        const float* __restrict__ wt, const float* __restrict__ bias,
        const unsigned int* __restrict__ wall, const float* __restrict__ rmax2,
        const int* __restrict__ offs, const unsigned int* __restrict__ lists,
        unsigned long long* __restrict__ maxn, unsigned int* __restrict__ gmax) {
    int bid = blockIdx.x;
    int sp = bid % 18;
    int bo = bid / 18;
    int b = bo & 7;
    int o = bo >> 3;
    int lane = threadIdx.x & 63, wv = threadIdx.x >> 6;
    int tile = sp * 4 + wv;
    if (tile >= 69) return;
    int tq = tile << 3;

    float bv = THETA_ * bias[o * 64 + lane];
    float RALL = 32.0f * __uint_as_float(wall[o]);
    const float* wto = wt + ((size_t)o * SYN_ << 6);
    const float* rmo = rmax2 + o * SYN_;
    const unsigned int* lst = lists + (size_t)b * LCAP_;
    const int* ob = offs + b * 501;
    unsigned long long* mb = maxn + (size_t)b * NT_ * 64;
    unsigned int* gb = gmax + b * NT_;

    float a[8];
    #pragma unroll
    for (int j = 0; j < 8; ++j) a[j] = bv;

    int thi = tq + 7; if (thi > T_) thi = T_;
    int tlo = (int)floorf((float)(tq - 1) - RALL) + 1;
    if (tlo < 0) tlo = 0;
    if (tlo > thi) tlo = thi;

    int i = ob[tlo], i1 = ob[thi];
    for (; i + 3 < i1; i += 4) {
        unsigned int e0 = lst[i], e1 = lst[i+1], e2 = lst[i+2], e3 = lst[i+3];
        int s0 = e0 & 0xFFFF, s1 = e1 & 0xFFFF, s2 = e2 & 0xFFFF, s3 = e3 & 0xFFFF;
        float rm0 = rmo[s0], rm1 = rmo[s1], rm2 = rmo[s2], rm3 = rmo[s3];
        float f0 = (float)(tq - 1 - (int)(e0 >> 16)) * 0.0625f;
        float f1 = (float)(tq - 1 - (int)(e1 >> 16)) * 0.0625f;
        float f2 = (float)(tq - 1 - (int)(e2 >> 16)) * 0.0625f;
        float f3 = (float)(tq - 1 - (int)(e3 >> 16)) * 0.0625f;
        if (f0 < rm0) { float w0 = wto[(s0 << 6) + lane]; SPIKE8(f0, w0); }
        if (f1 < rm1) { float w1 = wto[(s1 << 6) + lane]; SPIKE8(f1, w1); }
        if (f2 < rm2) { float w2 = wto[(s2 << 6) + lane]; SPIKE8(f2, w2); }
        if (f3 < rm3) { float w3 = wto[(s3 << 6) + lane]; SPIKE8(f3, w3); }
    }
    for (; i < i1; ++i) {
        unsigned int e = lst[i];
        int s = e & 0xFFFF;
        float f = (float)(tq - 1 - (int)(e >> 16)) * 0.0625f;
        if (f < rmo[s]) { float w = wto[(s << 6) + lane]; SPIKE8(f, w); }
    }

    #pragma unroll
    for (int j = 0; j < 8; ++j) {
        int tt = tq + j;
        if (tt >= NT_) break;
        float aj = a[j];
        if (__any(aj > THETA_)) {
            if (aj > THETA_) {
                unsigned long long key =
                    ((unsigned long long)__float_as_uint(aj) << 32) | (unsigned int)(9 - o);
                atomicMax(&mb[(size_t)tt * 64 + lane], key);
            }
            float m = aj;
            #pragma unroll
            for (int k = 32; k >= 1; k >>= 1) m = fmaxf(m, __shfl_xor(m, k));
            if (lane == 0) atomicMax(&gb[tt], __float_as_uint(m));
        }
    }
}

// K6: sequential k-WTA, one wave per batch (unchanged, twice-validated).
__global__ void wta2(const unsigned long long* __restrict__ maxn,
                     const unsigned int* __restrict__ gmax,
                     float* __restrict__ out) {
    int b = blockIdx.x;
    int lane = threadIdx.x;
    const unsigned long long* mb = maxn + (size_t)b * NT_ * 64;
    int dep = 0;
    for (int t0 = 0; t0 < NT_; t0 += 64) {
        int cl = NT_ - t0; if (cl > 64) cl = 64;
        float gv = (lane < cl) ? __uint_as_float(gmax[b * NT_ + t0 + lane]) : 0.f;
        unsigned long long mask = __ballot(gv > THETA_);
        int prev = -1;
        int p = 0;
        unsigned long long keyn = 0ull;
        if (mask) {
            p = __builtin_ctzll(mask);
            keyn = mb[(size_t)(t0 + p) * 64 + lane];
        }
        while (mask) {
            int pc = p;
            unsigned long long key = keyn;
            mask &= mask - 1;
            if (mask) {
                p = __builtin_ctzll(mask);
                keyn = mb[(size_t)(t0 + p) * 64 + lane];
            }
            dep -= (pc - prev - 1); if (dep < 0) dep = 0;
            prev = pc;
            unsigned long long db = __ballot(dep != 0);
            bool k_ok = __popcll(db) < 16;
            unsigned long long kv = (k_ok && dep == 0) ? key : 0ull;
            int idx = lane;
            #pragma unroll
            for (int k = 1; k < 64; k <<= 1) {
                unsigned long long ok2 = __shfl_xor(kv, k);
                int oi = __shfl_xor(idx, k);
                unsigned int vc = (unsigned int)(kv >> 32);
                unsigned int vo = (unsigned int)(ok2 >> 32);
                if (vo > vc || (vo == vc && oi < idx)) { kv = ok2; idx = oi; }
            }
            float val = __uint_as_float((unsigned int)(kv >> 32));
            if (val > THETA_) {
                int wo = 9 - (int)(kv & 0xFFFFFFFFull);
                if (lane == idx) {
                    out[((size_t)((b * OC_ + wo) * NEUR_ + idx)) * NT_ + (t0 + pc)] = 1.0f;
                    dep = 48;
                }
            }
            dep -= 1; if (dep < 0) dep = 0;
        }
        dep -= (cl - 1 - prev); if (dep < 0) dep = 0;
    }
}

extern "C" void kernel_launch(void* const* d_in, const int* in_sizes, int n_in,
                              void* d_out, int out_size, void* d_ws, size_t ws_size,
                              hipStream_t stream) {
    const float* x      = (const float*)d_in[0];   // [8,1,512,500]
    const float* weight = (const float*)d_in[1];   // [640,512]
    const float* bias   = (const float*)d_in[2];   // [640]
    float* out = (float*)d_out;

    char* ws = (char*)d_ws;
    int*                offs  = (int*)(ws + OFFS_OFF);
    unsigned int*       lists = (unsigned int*)(ws + LIST_OFF);
    float*              wt    = (float*)(ws + WT_OFF);
    unsigned int*       wall  = (unsigned int*)(ws + WALL_OFF);
    float*              rmax2 = (float*)(ws + RMAX_OFF);
    unsigned long long* maxn  = (unsigned long long*)(ws + MAXN_OFF);
    unsigned int*       gmaxp = (unsigned int*)(ws + GMAX_OFF);
    int*                cnt   = (int*)(ws + CNT_OFF);

    hipLaunchKernelGGL(count_zero, dim3(64), dim3(64), 0, stream,
                       x, cnt, (float4*)out, out_size / 4, (float4*)(ws + MAXN_OFF), wall);
    hipLaunchKernelGGL(scan_offs, dim3(B_), dim3(512), 0, stream, cnt, offs);
    hipLaunchKernelGGL(fill_lists, dim3(64), dim3(64), 0, stream, x, offs, lists);
    hipLaunchKernelGGL(prep2, dim3(40), dim3(128), 0, stream, weight, wt, rmax2, wall);
    hipLaunchKernelGGL(conv4, dim3(1440), dim3(256), 0, stream,
                       wt, bias, wall, rmax2, offs, lists, maxn, gmaxp);
    hipLaunchKernelGGL(wta2, dim3(B_), dim3(64), 0, stream, maxn, gmaxp, out);
}

// Round 16
// 243.076 us; speedup vs baseline: 1.9164x; 1.1718x over previous
//
#include <hip/hip_runtime.h>
#include <hip/hip_bf16.h>
#include <cstdint>

#define B_ 8
#define SYN_ 512
#define T_ 500
#define NT_ 549        // output timesteps
#define OC_ 10
#define NEUR_ 64
#define LCAP_ 8192
#define THETA_ 25.6f

// ---------------- workspace layout (bytes) ----------------
#define OFFS_OFF  0          // [B][501] int              (16,032)
#define LIST_OFF  16384      // [B][LCAP] u32             (262,144)
#define WT_OFF    278528     // [OC][SYN][64] f32 1.5*tanh (1,310,720)
#define WALL_OFF  1589248    // [OC] u32 max w15 per o    (40)
#define RMAX_OFF  1589504    // [OC][SYN] f32 2*max_n w15 (20,480)
#define MAXN_OFF  1610240    // [B][NT][64] u64 keys      (2,248,704)
#define GMAX_OFF  3859200    // [B][NT] u32               (17,568)
#define CNT_OFF   3877120    // [B][512] int              (16,384)
#define NMZ4 ((GMAX_OFF + 17568 - MAXN_OFF) / 16)   // zero range maxn..gmax

// K1: 64 blocks x 64 thr. Zero out/maxn/gmax/wall + per-(b,t) spike counts.
__global__ __launch_bounds__(64) void count_zero(
        const float* __restrict__ x, int* __restrict__ cnt,
        float4* __restrict__ out4, int nout4, float4* __restrict__ mz4,
        unsigned int* __restrict__ wall) {
    int i = blockIdx.x * 64 + threadIdx.x;   // 0..4095
    int nt = gridDim.x * 64;
    float4 z = make_float4(0.f, 0.f, 0.f, 0.f);
    for (int k = i; k < nout4; k += nt) out4[k] = z;
    for (int k = i; k < NMZ4; k += nt) mz4[k] = z;
    if (i < OC_) wall[i] = 0u;
    int b = i >> 9, t = i & 511;
    if (t < T_) {
        const float* xb = x + (size_t)b * SYN_ * T_ + t;
        int c = 0;
        #pragma unroll 8
        for (int s = 0; s < SYN_; ++s) c += (xb[s * T_] != 0.0f);
        cnt[(b << 9) | t] = c;
    }
}

// K2: exclusive scan of per-t counts -> offs. 8 blocks x 512.
__global__ void scan_offs(const int* __restrict__ cnt, int* __restrict__ offs) {
    int b = blockIdx.x, tid = threadIdx.x;
    __shared__ int incl[512];
    incl[tid] = (tid < T_) ? cnt[(b << 9) | tid] : 0;
    __syncthreads();
    for (int off = 1; off < 512; off <<= 1) {
        int v = incl[tid];
        int add = (tid >= off) ? incl[tid - off] : 0;
        __syncthreads();
        incl[tid] = v + add;
        __syncthreads();
    }
    if (tid < T_) offs[b * 501 + tid] = tid ? incl[tid - 1] : 0;
    if (tid == 0) offs[b * 501 + T_] = incl[T_ - 1];
}

// K3: fill s-sorted per-t lists. Thread owns (b,t). 16-wide load batches:
// issue 16 independent coalesced loads, THEN the serial test/write pass --
// breaks the load->branch->cur++ serialization that made v1 latency-bound
// (142us at MLP~1; 16x MLP -> ~32 HBM round trips total).
__global__ __launch_bounds__(64) void fill_lists(
        const float* __restrict__ x, const int* __restrict__ offs,
        unsigned int* __restrict__ lists) {
    int i = blockIdx.x * 64 + threadIdx.x;
    int b = i >> 9, t = i & 511;
    if (t >= T_) return;
    const float* xb = x + (size_t)b * SYN_ * T_ + t;
    int cur = offs[b * 501 + t];
    unsigned int* lb = lists + (size_t)b * LCAP_;
    unsigned int tb = (unsigned int)t << 16;
    for (int s0 = 0; s0 < SYN_; s0 += 16) {
        float v[16];
        #pragma unroll
        for (int k = 0; k < 16; ++k) v[k] = xb[(s0 + k) * T_];
        #pragma unroll
        for (int k = 0; k < 16; ++k) {
            if (v[k] != 0.0f) {
                if (cur < LCAP_) lb[cur] = tb | (unsigned int)(s0 + k);
                ++cur;
            }
        }
    }
}

// K4: wt[o][s][n]=1.5*tanh(w) via LDS 64x64 transpose; rmax2[o][s]; wall[o].
__global__ __launch_bounds__(128) void prep2(
        const float* __restrict__ weight, float* __restrict__ wt,
        float* __restrict__ rmax2, unsigned int* __restrict__ wall) {
    __shared__ float tile[2][64][65];
    int wv = threadIdx.x >> 6, lane = threadIdx.x & 63;
    int tid4 = blockIdx.x * 2 + wv;          // 0..79
    int o = tid4 >> 3, sc = (tid4 & 7) << 6;
    float (*td)[65] = tile[wv];
    float mx = 0.f;
    for (int n = 0; n < 64; ++n) {
        float w15 = 1.5f * tanhf(weight[(size_t)(o * 64 + n) * SYN_ + sc + lane]);
        td[n][lane] = w15;
        mx = fmaxf(mx, w15);
    }
    rmax2[o * SYN_ + sc + lane] = 2.0f * mx;
    float wm = mx;
    #pragma unroll
    for (int k = 32; k >= 1; k >>= 1) wm = fmaxf(wm, __shfl_xor(wm, k));
    if (lane == 0) atomicMax(&wall[o], __float_as_uint(wm));
    for (int r = 0; r < 64; ++r)
        wt[((size_t)(o * SYN_ + sc + r) << 6) + lane] = td[lane][r];
}

// K5: sparse conv, 8-output tiles, 4-spike batches, per-(o,s) rmax gate.
#define SPIKE8(F, W) { \
    _Pragma("unroll") \
    for (int j = 0; j < 8; ++j) { \
        float ts = (F) + (float)j * 0.0625f; \
        a[j] += __builtin_amdgcn_fmed3f(0.0f, ts, fmaf(ts, -0.5f, (W))); \
    } }

__global__ __launch_bounds__(256) void conv4(
        const float* __restrict__ wt, const float* __restrict__ bias,
        const unsigned int* __restrict__ wall, const float* __restrict__ rmax2,
        const int* __restrict__ offs, const unsigned int* __restrict__ lists,
        unsigned long long* __restrict__ maxn, unsigned int* __restrict__ gmax) {
    int bid = blockIdx.x;
    int sp = bid % 18;
    int bo = bid / 18;
    int b = bo & 7;
    int o = bo >> 3;
    int lane = threadIdx.x & 63, wv = threadIdx.x >> 6;
    int tile = sp * 4 + wv;
    if (tile >= 69) return;
    int tq = tile << 3;

    float bv = THETA_ * bias[o * 64 + lane];
    float RALL = 32.0f * __uint_as_float(wall[o]);
    const float* wto = wt + ((size_t)o * SYN_ << 6);
    const float* rmo = rmax2 + o * SYN_;
    const unsigned int* lst = lists + (size_t)b * LCAP_;
    const int* ob = offs + b * 501;
    unsigned long long* mb = maxn + (size_t)b * NT_ * 64;
    unsigned int* gb = gmax + b * NT_;

    float a[8];
    #pragma unroll
    for (int j = 0; j < 8; ++j) a[j] = bv;

    int thi = tq + 7; if (thi > T_) thi = T_;
    int tlo = (int)floorf((float)(tq - 1) - RALL) + 1;
    if (tlo < 0) tlo = 0;
    if (tlo > thi) tlo = thi;

    int i = ob[tlo], i1 = ob[thi];
    for (; i + 3 < i1; i += 4) {
        unsigned int e0 = lst[i], e1 = lst[i+1], e2 = lst[i+2], e3 = lst[i+3];
        int s0 = e0 & 0xFFFF, s1 = e1 & 0xFFFF, s2 = e2 & 0xFFFF, s3 = e3 & 0xFFFF;
        float rm0 = rmo[s0], rm1 = rmo[s1], rm2 = rmo[s2], rm3 = rmo[s3];
        float f0 = (float)(tq - 1 - (int)(e0 >> 16)) * 0.0625f;
        float f1 = (float)(tq - 1 - (int)(e1 >> 16)) * 0.0625f;
        float f2 = (float)(tq - 1 - (int)(e2 >> 16)) * 0.0625f;
        float f3 = (float)(tq - 1 - (int)(e3 >> 16)) * 0.0625f;
        if (f0 < rm0) { float w0 = wto[(s0 << 6) + lane]; SPIKE8(f0, w0); }
        if (f1 < rm1) { float w1 = wto[(s1 << 6) + lane]; SPIKE8(f1, w1); }
        if (f2 < rm2) { float w2 = wto[(s2 << 6) + lane]; SPIKE8(f2, w2); }
        if (f3 < rm3) { float w3 = wto[(s3 << 6) + lane]; SPIKE8(f3, w3); }
    }
    for (; i < i1; ++i) {
        unsigned int e = lst[i];
        int s = e & 0xFFFF;
        float f = (float)(tq - 1 - (int)(e >> 16)) * 0.0625f;
        if (f < rmo[s]) { float w = wto[(s << 6) + lane]; SPIKE8(f, w); }
    }

    #pragma unroll
    for (int j = 0; j < 8; ++j) {
        int tt = tq + j;
        if (tt >= NT_) break;
        float aj = a[j];
        if (__any(aj > THETA_)) {
            if (aj > THETA_) {
                unsigned long long key =
                    ((unsigned long long)__float_as_uint(aj) << 32) | (unsigned int)(9 - o);
                atomicMax(&mb[(size_t)tt * 64 + lane], key);
            }
            float m = aj;
            #pragma unroll
            for (int k = 32; k >= 1; k >>= 1) m = fmaxf(m, __shfl_xor(m, k));
            if (lane == 0) atomicMax(&gb[tt], __float_as_uint(m));
        }
    }
}

// K6: sequential k-WTA, one wave per batch (unchanged, thrice-validated).
__global__ void wta2(const unsigned long long* __restrict__ maxn,
                     const unsigned int* __restrict__ gmax,
                     float* __restrict__ out) {
    int b = blockIdx.x;
    int lane = threadIdx.x;
    const unsigned long long* mb = maxn + (size_t)b * NT_ * 64;
    int dep = 0;
    for (int t0 = 0; t0 < NT_; t0 += 64) {
        int cl = NT_ - t0; if (cl > 64) cl = 64;
        float gv = (lane < cl) ? __uint_as_float(gmax[b * NT_ + t0 + lane]) : 0.f;
        unsigned long long mask = __ballot(gv > THETA_);
        int prev = -1;
        int p = 0;
        unsigned long long keyn = 0ull;
        if (mask) {
            p = __builtin_ctzll(mask);
            keyn = mb[(size_t)(t0 + p) * 64 + lane];
        }
        while (mask) {
            int pc = p;
            unsigned long long key = keyn;
            mask &= mask - 1;
            if (mask) {
                p = __builtin_ctzll(mask);
                keyn = mb[(size_t)(t0 + p) * 64 + lane];
            }
            dep -= (pc - prev - 1); if (dep < 0) dep = 0;
            prev = pc;
            unsigned long long db = __ballot(dep != 0);
            bool k_ok = __popcll(db) < 16;
            unsigned long long kv = (k_ok && dep == 0) ? key : 0ull;
            int idx = lane;
            #pragma unroll
            for (int k = 1; k < 64; k <<= 1) {
                unsigned long long ok2 = __shfl_xor(kv, k);
                int oi = __shfl_xor(idx, k);
                unsigned int vc = (unsigned int)(kv >> 32);
                unsigned int vo = (unsigned int)(ok2 >> 32);
                if (vo > vc || (vo == vc && oi < idx)) { kv = ok2; idx = oi; }
            }
            float val = __uint_as_float((unsigned int)(kv >> 32));
            if (val > THETA_) {
                int wo = 9 - (int)(kv & 0xFFFFFFFFull);
                if (lane == idx) {
                    out[((size_t)((b * OC_ + wo) * NEUR_ + idx)) * NT_ + (t0 + pc)] = 1.0f;
                    dep = 48;
                }
            }
            dep -= 1; if (dep < 0) dep = 0;
        }
        dep -= (cl - 1 - prev); if (dep < 0) dep = 0;
    }
}

extern "C" void kernel_launch(void* const* d_in, const int* in_sizes, int n_in,
                              void* d_out, int out_size, void* d_ws, size_t ws_size,
                              hipStream_t stream) {
    const float* x      = (const float*)d_in[0];   // [8,1,512,500]
    const float* weight = (const float*)d_in[1];   // [640,512]
    const float* bias   = (const float*)d_in[2];   // [640]
    float* out = (float*)d_out;

    char* ws = (char*)d_ws;
    int*                offs  = (int*)(ws + OFFS_OFF);
    unsigned int*       lists = (unsigned int*)(ws + LIST_OFF);
    float*              wt    = (float*)(ws + WT_OFF);
    unsigned int*       wall  = (unsigned int*)(ws + WALL_OFF);
    float*              rmax2 = (float*)(ws + RMAX_OFF);
    unsigned long long* maxn  = (unsigned long long*)(ws + MAXN_OFF);
    unsigned int*       gmaxp = (unsigned int*)(ws + GMAX_OFF);
    int*                cnt   = (int*)(ws + CNT_OFF);

    hipLaunchKernelGGL(count_zero, dim3(64), dim3(64), 0, stream,
                       x, cnt, (float4*)out, out_size / 4, (float4*)(ws + MAXN_OFF), wall);
    hipLaunchKernelGGL(scan_offs, dim3(B_), dim3(512), 0, stream, cnt, offs);
    hipLaunchKernelGGL(fill_lists, dim3(64), dim3(64), 0, stream, x, offs, lists);
    hipLaunchKernelGGL(prep2, dim3(40), dim3(128), 0, stream, weight, wt, rmax2, wall);
    hipLaunchKernelGGL(conv4, dim3(1440), dim3(256), 0, stream,
                       wt, bias, wall, rmax2, offs, lists, maxn, gmaxp);
    hipLaunchKernelGGL(wta2, dim3(B_), dim3(64), 0, stream, maxn, gmaxp, out);
}

// Round 17
// 204.943 us; speedup vs baseline: 2.2730x; 1.1861x over previous
//
#include <hip/hip_runtime.h>
#include <hip/hip_bf16.h>
#include <cstdint>

#define B_ 8
#define SYN_ 512
#define T_ 500
#define NT_ 549        // output timesteps
#define OC_ 10
#define NEUR_ 64
#define LCAP_ 8192
#define THETA_ 25.6f

// ---------------- workspace layout (bytes) ----------------
#define OFFS_OFF  0          // [B][501] int              (16,032)
#define LIST_OFF  16384      // [B][LCAP] u32             (262,144)
#define WT_OFF    278528     // [OC][SYN][64] f32 1.5*tanh (1,310,720)
#define WALL_OFF  1589248    // [OC] u32 max w15 per o    (40)
#define RMAX_OFF  1589504    // [OC][SYN] f32 2*max_n w15 (20,480)
#define MAXN_OFF  1610240    // [B][NT][64] u64 keys      (2,248,704)
#define GMAX_OFF  3859200    // [B][NT] u32               (17,568)
#define NMZ4 ((GMAX_OFF + 17568 - MAXN_OFF) / 16)   // zero range maxn..gmax

// K1: grid-stride zero of out + maxn..gmax + wall. 256x256.
__global__ __launch_bounds__(256) void zero3(
        float4* __restrict__ out4, int nout4, float4* __restrict__ mz4,
        unsigned int* __restrict__ wall) {
    int i = blockIdx.x * 256 + threadIdx.x;
    int nt = gridDim.x * 256;
    float4 z = make_float4(0.f, 0.f, 0.f, 0.f);
    for (int k = i; k < nout4; k += nt) out4[k] = z;
    for (int k = i; k < NMZ4; k += nt) mz4[k] = z;
    if (i < OC_) wall[i] = 0u;
}

// K2: fused count+scan+fill, 8 blocks x 512. Thread owns (b,t): reads its
// x column ONCE in 32-wide batches (MLP breaks the 900cy/elem serialization
// that cost 142us in v1), keeps occupancy bits in 16 register words, scans
// counts in LDS, then emits list entries by ctz-walking the register masks
// (LSB-first = s-ascending, same order as all passing runs). No 2nd x read.
__global__ __launch_bounds__(512) void build2(
        const float* __restrict__ x, int* __restrict__ offs,
        unsigned int* __restrict__ lists) {
    int b = blockIdx.x, tid = threadIdx.x;
    __shared__ int incl[512];
    unsigned int m[16];
    int c = 0;
    if (tid < T_) {
        const float* xb = x + (size_t)b * SYN_ * T_ + tid;
        #pragma unroll
        for (int g = 0; g < 16; ++g) {
            float v[32];
            #pragma unroll
            for (int k = 0; k < 32; ++k) v[k] = xb[(g * 32 + k) * T_];
            unsigned int mm = 0u;
            #pragma unroll
            for (int k = 0; k < 32; ++k) if (v[k] != 0.0f) mm |= (1u << k);
            m[g] = mm;
            c += __popc(mm);
        }
    }
    incl[tid] = c;
    __syncthreads();
    for (int off = 1; off < 512; off <<= 1) {
        int v = incl[tid];
        int add = (tid >= off) ? incl[tid - off] : 0;
        __syncthreads();
        incl[tid] = v + add;
        __syncthreads();
    }
    if (tid < T_) offs[b * 501 + tid] = tid ? incl[tid - 1] : 0;
    if (tid == 0) offs[b * 501 + T_] = incl[T_ - 1];
    if (tid < T_ && c > 0) {
        int cur = tid ? incl[tid - 1] : 0;
        unsigned int* lb = lists + (size_t)b * LCAP_;
        unsigned int tb = (unsigned int)tid << 16;
        #pragma unroll
        for (int g = 0; g < 16; ++g) {
            unsigned int mm = m[g];
            while (mm) {
                int k = __builtin_ctz(mm);
                mm &= mm - 1;
                if (cur < LCAP_) lb[cur] = tb | (unsigned int)(g * 32 + k);
                ++cur;
            }
        }
    }
}

// K3: wt[o][s][n]=1.5*tanh(w) via LDS 64x64 transpose; rmax2[o][s]; wall[o].
__global__ __launch_bounds__(128) void prep2(
        const float* __restrict__ weight, float* __restrict__ wt,
        float* __restrict__ rmax2, unsigned int* __restrict__ wall) {
    __shared__ float tile[2][64][65];
    int wv = threadIdx.x >> 6, lane = threadIdx.x & 63;
    int tid4 = blockIdx.x * 2 + wv;          // 0..79
    int o = tid4 >> 3, sc = (tid4 & 7) << 6;
    float (*td)[65] = tile[wv];
    float mx = 0.f;
    for (int n = 0; n < 64; ++n) {
        float w15 = 1.5f * tanhf(weight[(size_t)(o * 64 + n) * SYN_ + sc + lane]);
        td[n][lane] = w15;
        mx = fmaxf(mx, w15);
    }
    rmax2[o * SYN_ + sc + lane] = 2.0f * mx;
    float wm = mx;
    #pragma unroll
    for (int k = 32; k >= 1; k >>= 1) wm = fmaxf(wm, __shfl_xor(wm, k));
    if (lane == 0) atomicMax(&wall[o], __float_as_uint(wm));
    for (int r = 0; r < 64; ++r)
        wt[((size_t)(o * SYN_ + sc + r) << 6) + lane] = td[lane][r];
}

// K4: sparse conv. v4b: ALL loads (4 rm + 4 w) issued unconditionally up
// front (MLP=8, the conv3 pattern), gate only the SPIKE8 compute -- the v4
// rm->branch->w chain serialized two L2 round trips per spike (104us,
// VALUBusy fell 81->63%). Skipped terms are exactly 0.0f -> bit-exact.
#define SPIKE8(F, W) { \
    _Pragma("unroll") \
    for (int j = 0; j < 8; ++j) { \
        float ts = (F) + (float)j * 0.0625f; \
        a[j] += __builtin_amdgcn_fmed3f(0.0f, ts, fmaf(ts, -0.5f, (W))); \
    } }

__global__ __launch_bounds__(256) void conv4b(
        const float* __restrict__ wt, const float* __restrict__ bias,
        const unsigned int* __restrict__ wall, const float* __restrict__ rmax2,
        const int* __restrict__ offs, const unsigned int* __restrict__ lists,
        unsigned long long* __restrict__ maxn, unsigned int* __restrict__ gmax) {
    int bid = blockIdx.x;
    int sp = bid % 18;
    int bo = bid / 18;
    int b = bo & 7;
    int o = bo >> 3;
    int lane = threadIdx.x & 63, wv = threadIdx.x >> 6;
    int tile = sp * 4 + wv;
    if (tile >= 69) return;
    int tq = tile << 3;

    float bv = THETA_ * bias[o * 64 + lane];
    float RALL = 32.0f * __uint_as_float(wall[o]);
    const float* wto = wt + ((size_t)o * SYN_ << 6);
    const float* rmo = rmax2 + o * SYN_;
    const unsigned int* lst = lists + (size_t)b * LCAP_;
    const int* ob = offs + b * 501;
    unsigned long long* mb = maxn + (size_t)b * NT_ * 64;
    unsigned int* gb = gmax + b * NT_;

    float a[8];
    #pragma unroll
    for (int j = 0; j < 8; ++j) a[j] = bv;

    int thi = tq + 7; if (thi > T_) thi = T_;
    int tlo = (int)floorf((float)(tq - 1) - RALL) + 1;
    if (tlo < 0) tlo = 0;
    if (tlo > thi) tlo = thi;

    int i = ob[tlo], i1 = ob[thi];
    for (; i + 3 < i1; i += 4) {
        unsigned int e0 = lst[i], e1 = lst[i+1], e2 = lst[i+2], e3 = lst[i+3];
        int s0 = e0 & 0xFFFF, s1 = e1 & 0xFFFF, s2 = e2 & 0xFFFF, s3 = e3 & 0xFFFF;
        float rm0 = rmo[s0], rm1 = rmo[s1], rm2 = rmo[s2], rm3 = rmo[s3];
        float w0 = wto[(s0 << 6) + lane];
        float w1 = wto[(s1 << 6) + lane];
        float w2 = wto[(s2 << 6) + lane];
        float w3 = wto[(s3 << 6) + lane];
        float f0 = (float)(tq - 1 - (int)(e0 >> 16)) * 0.0625f;
        float f1 = (float)(tq - 1 - (int)(e1 >> 16)) * 0.0625f;
        float f2 = (float)(tq - 1 - (int)(e2 >> 16)) * 0.0625f;
        float f3 = (float)(tq - 1 - (int)(e3 >> 16)) * 0.0625f;
        if (f0 < rm0) SPIKE8(f0, w0);
        if (f1 < rm1) SPIKE8(f1, w1);
        if (f2 < rm2) SPIKE8(f2, w2);
        if (f3 < rm3) SPIKE8(f3, w3);
    }
    for (; i < i1; ++i) {
        unsigned int e = lst[i];
        int s = e & 0xFFFF;
        float rm = rmo[s];
        float w = wto[(s << 6) + lane];
        float f = (float)(tq - 1 - (int)(e >> 16)) * 0.0625f;
        if (f < rm) SPIKE8(f, w);
    }

    #pragma unroll
    for (int j = 0; j < 8; ++j) {
        int tt = tq + j;
        if (tt >= NT_) break;
        float aj = a[j];
        if (__any(aj > THETA_)) {
            if (aj > THETA_) {
                unsigned long long key =
                    ((unsigned long long)__float_as_uint(aj) << 32) | (unsigned int)(9 - o);
                atomicMax(&mb[(size_t)tt * 64 + lane], key);
            }
            float m = aj;
            #pragma unroll
            for (int k = 32; k >= 1; k >>= 1) m = fmaxf(m, __shfl_xor(m, k));
            if (lane == 0) atomicMax(&gb[tt], __float_as_uint(m));
        }
    }
}

// K5: sequential k-WTA, one wave per batch (unchanged, thrice-validated).
__global__ void wta2(const unsigned long long* __restrict__ maxn,
                     const unsigned int* __restrict__ gmax,
                     float* __restrict__ out) {
    int b = blockIdx.x;
    int lane = threadIdx.x;
    const unsigned long long* mb = maxn + (size_t)b * NT_ * 64;
    int dep = 0;
    for (int t0 = 0; t0 < NT_; t0 += 64) {
        int cl = NT_ - t0; if (cl > 64) cl = 64;
        float gv = (lane < cl) ? __uint_as_float(gmax[b * NT_ + t0 + lane]) : 0.f;
        unsigned long long mask = __ballot(gv > THETA_);
        int prev = -1;
        int p = 0;
        unsigned long long keyn = 0ull;
        if (mask) {
            p = __builtin_ctzll(mask);
            keyn = mb[(size_t)(t0 + p) * 64 + lane];
        }
        while (mask) {
            int pc = p;
            unsigned long long key = keyn;
            mask &= mask - 1;
            if (mask) {
                p = __builtin_ctzll(mask);
                keyn = mb[(size_t)(t0 + p) * 64 + lane];
            }
            dep -= (pc - prev - 1); if (dep < 0) dep = 0;
            prev = pc;
            unsigned long long db = __ballot(dep != 0);
            bool k_ok = __popcll(db) < 16;
            unsigned long long kv = (k_ok && dep == 0) ? key : 0ull;
            int idx = lane;
            #pragma unroll
            for (int k = 1; k < 64; k <<= 1) {
                unsigned long long ok2 = __shfl_xor(kv, k);
                int oi = __shfl_xor(idx, k);
                unsigned int vc = (unsigned int)(kv >> 32);
                unsigned int vo = (unsigned int)(ok2 >> 32);
                if (vo > vc || (vo == vc && oi < idx)) { kv = ok2; idx = oi; }
            }
            float val = __uint_as_float((unsigned int)(kv >> 32));
            if (val > THETA_) {
                int wo = 9 - (int)(kv & 0xFFFFFFFFull);
                if (lane == idx) {
                    out[((size_t)((b * OC_ + wo) * NEUR_ + idx)) * NT_ + (t0 + pc)] = 1.0f;
                    dep = 48;
                }
            }
            dep -= 1; if (dep < 0) dep = 0;
        }
        dep -= (cl - 1 - prev); if (dep < 0) dep = 0;
    }
}

extern "C" void kernel_launch(void* const* d_in, const int* in_sizes, int n_in,
                              void* d_out, int out_size, void* d_ws, size_t ws_size,
                              hipStream_t stream) {
    const float* x      = (const float*)d_in[0];   // [8,1,512,500]
    const float* weight = (const float*)d_in[1];   // [640,512]
    const float* bias   = (const float*)d_in[2];   // [640]
    float* out = (float*)d_out;

    char* ws = (char*)d_ws;
    int*                offs  = (int*)(ws + OFFS_OFF);
    unsigned int*       lists = (unsigned int*)(ws + LIST_OFF);
    float*              wt    = (float*)(ws + WT_OFF);
    unsigned int*       wall  = (unsigned int*)(ws + WALL_OFF);
    float*              rmax2 = (float*)(ws + RMAX_OFF);
    unsigned long long* maxn  = (unsigned long long*)(ws + MAXN_OFF);
    unsigned int*       gmaxp = (unsigned int*)(ws + GMAX_OFF);

    hipLaunchKernelGGL(zero3, dim3(256), dim3(256), 0, stream,
                       (float4*)out, out_size / 4, (float4*)(ws + MAXN_OFF), wall);
    hipLaunchKernelGGL(build2, dim3(B_), dim3(512), 0, stream, x, offs, lists);
    hipLaunchKernelGGL(prep2, dim3(40), dim3(128), 0, stream, weight, wt, rmax2, wall);
    hipLaunchKernelGGL(conv4b, dim3(1440), dim3(256), 0, stream,
                       wt, bias, wall, rmax2, offs, lists, maxn, gmaxp);
    hipLaunchKernelGGL(wta2, dim3(B_), dim3(64), 0, stream, maxn, gmaxp, out);
}